// Round 2
// baseline (591.104 us; speedup 1.0000x reference)
//
#include <hip/hip_runtime.h>
#include <hip/hip_bf16.h>

typedef unsigned short u16;
typedef unsigned int   u32;
typedef unsigned long long u64;
typedef __bf16 bfv8 __attribute__((ext_vector_type(8)));
typedef float  fv4  __attribute__((ext_vector_type(4)));
typedef u32    uv4  __attribute__((ext_vector_type(4)));

// ---- helpers ----
static __device__ __forceinline__ u16 f2bf(float f) {
    unsigned u = __builtin_bit_cast(unsigned, f);
    unsigned r = (u + 0x7fffu + ((u >> 16) & 1u)) >> 16;
    return (u16)r;
}

static __device__ __forceinline__ u32 cvtpk(float a, float b) {
    u32 r;
    asm("v_cvt_pk_bf16_f32 %0, %1, %2" : "=v"(r) : "v"(a), "v"(b));
    return r;
}

static __device__ __forceinline__ void gld16(const void* g, void* l) {
    __builtin_amdgcn_global_load_lds(
        (const __attribute__((address_space(1))) void*)g,
        (__attribute__((address_space(3))) void*)l, 16, 0, 0);
}

// ---------------------------------------------------------------------------
// Kernel 0: fp32 -> bf16 conversion of x, Wq, Wk, Wv, Wo (contiguous in ws)
// ---------------------------------------------------------------------------
__global__ __launch_bounds__(256) void cvt_f32_bf16(
    const float* __restrict__ x, const float* __restrict__ wq,
    const float* __restrict__ wk, const float* __restrict__ wv,
    const float* __restrict__ wo, u16* __restrict__ dst)
{
    int i = blockIdx.x * 256 + threadIdx.x;      // float4 index
    const int NX4 = 6291456 / 4;
    const int NW4 = 589824 / 4;
    const float4* src;
    int j = i;
    if (j < NX4) { src = (const float4*)x; }
    else {
        j -= NX4;
        if (j < NW4) { src = (const float4*)wq; }
        else {
            j -= NW4;
            if (j < NW4) { src = (const float4*)wk; }
            else {
                j -= NW4;
                if (j < NW4) { src = (const float4*)wv; }
                else { j -= NW4; src = (const float4*)wo; }
            }
        }
    }
    float4 v = src[j];
    u64 pk = (u64)f2bf(v.x) | ((u64)f2bf(v.y) << 16) |
             ((u64)f2bf(v.z) << 32) | ((u64)f2bf(v.w) << 48);
    *(u64*)(dst + (size_t)i * 4) = pk;
}

// ---------------------------------------------------------------------------
// Generic GEMM: C[M=8192][N=768] = (A[8192][768] @ Bw[768][768]^T + bias)*scale
// mode 1: write bf16 to [B,H,Dh,N]  (v transposed)
// mode 2: write fp32 row-major      (final output)
// mode 3: write bf16 row-major      (q, k)
// ---------------------------------------------------------------------------
__global__ __launch_bounds__(256) void gemm_bt(
    const u16* __restrict__ A, const u16* __restrict__ Bw,
    const float* __restrict__ bias, u16* __restrict__ Cb,
    float* __restrict__ Cf, float scale, int mode)
{
    __shared__ alignas(16) u16 lA[128 * 32];
    __shared__ alignas(16) u16 lB[128 * 32];
    const int t = threadIdx.x;
    const int w = t >> 6, l = t & 63;
    const int l15 = l & 15, l4 = l >> 4;
    const int bx = blockIdx.x, by = blockIdx.y;
    const int wr = (w >> 1) * 64, wc = (w & 1) * 64;
    const int srow = t >> 2;
    const int sg = t & 3;

    fv4 acc[4][4] = {};

    for (int kt = 0; kt < 24; ++kt) {
        const int kof = kt * 32;
        #pragma unroll
        for (int is = 0; is < 2; ++is) {
            int row = is * 64 + srow;
            int gs = sg ^ ((row >> 1) & 3);
            gld16(A + (size_t)(bx * 128 + row) * 768 + kof + gs * 8,
                  &lA[row * 32 + sg * 8]);
            gld16(Bw + (size_t)(by * 128 + row) * 768 + kof + gs * 8,
                  &lB[row * 32 + sg * 8]);
        }
        __syncthreads();

        bfv8 aF[4], bF[4];
        #pragma unroll
        for (int f = 0; f < 4; ++f) {
            int ra = wr + f * 16 + l15;
            aF[f] = *(const bfv8*)&lA[ra * 32 + (l4 ^ ((ra >> 1) & 3)) * 8];
            int rb = wc + f * 16 + l15;
            bF[f] = *(const bfv8*)&lB[rb * 32 + (l4 ^ ((rb >> 1) & 3)) * 8];
        }
        #pragma unroll
        for (int fm = 0; fm < 4; ++fm)
            #pragma unroll
            for (int fn = 0; fn < 4; ++fn)
                acc[fm][fn] = __builtin_amdgcn_mfma_f32_16x16x32_bf16(
                    aF[fm], bF[fn], acc[fm][fn], 0, 0, 0);
        __syncthreads();
    }

    #pragma unroll
    for (int fm = 0; fm < 4; ++fm) {
        #pragma unroll
        for (int fn = 0; fn < 4; ++fn) {
            int n = by * 128 + wc + fn * 16 + l15;
            float bs = bias[n];
            #pragma unroll
            for (int rr = 0; rr < 4; ++rr) {
                int m = bx * 128 + wr + fm * 16 + l4 * 4 + rr;
                float v = (acc[fm][fn][rr] + bs) * scale;
                if (mode == 2) {
                    Cf[(size_t)m * 768 + n] = v;
                } else if (mode == 3) {
                    Cb[(size_t)m * 768 + n] = f2bf(v);
                } else {           // mode 1: V^T [B,H,Dh,N]
                    int b = m >> 10, tok = m & 1023;
                    int h = n >> 6, dl = n & 63;
                    Cb[((size_t)(b * 12 + h) * 64 + dl) * 1024 + tok] = f2bf(v);
                }
            }
        }
    }
}

// ---------------------------------------------------------------------------
// Fused scores + head-softmax + PV.
// WG = 128 threads (2 waves). Wave mh handles m-half [mh*512, mh*512+512).
// Both waves: same 16-row n-block. Pair-reduce over m-halves via LDS.
// qb, kb: bf16 row-major [8192][768] (q pre-scaled by 0.125*log2e).
// vtb:    bf16 [B,H,Dh,N].   ctx out: bf16 [B,N,768].
// Per m-tile of 32: S^T = mfma(K,Q) per head -> lane(l15=n) holds
// P[n][m = mf*16+l4*4+rr]; pack to K=32 A-frag slots j=mf*4+rr and load V^T
// with the matching permuted k-map m(l4,j) = (j>>2)*16 + l4*4 + (j&3).
// ---------------------------------------------------------------------------
__global__ __launch_bounds__(128, 1) void fused_attn(
    const u16* __restrict__ qb, const u16* __restrict__ kb,
    const u16* __restrict__ vtb, u16* __restrict__ ctx)
{
    __shared__ fv4 red[12 * 4 * 64];     // 48 KB (pair-reduce)
    const int t = threadIdx.x;
    const int mh = t >> 6;               // wave id = m-half
    const int l = t & 63, l15 = l & 15, l4 = l >> 4;
    const int b = blockIdx.y;
    const int nbase = blockIdx.x * 16;

    // Q fragments (B-operand): lane l15 = n-local; 12h x 2ks
    bfv8 Qf[12][2];
    const u16* qrow = qb + (size_t)(b * 1024 + nbase + l15) * 768;
    #pragma unroll
    for (int h = 0; h < 12; ++h)
        #pragma unroll
        for (int ks = 0; ks < 2; ++ks)
            Qf[h][ks] = *(const bfv8*)(qrow + h * 64 + ks * 32 + l4 * 8);

    fv4 acc[12][4] = {};   // [h][dn]: out rows n=l4*4+rr, cols d=dn*16+l15

    for (int mt = 0; mt < 16; ++mt) {
        const int mbase = mh * 512 + mt * 32;

        // ---- scores + exp (no max-subtraction; scale folded into q) ----
        fv4 E[12][2];
        fv4 dsum[2] = {};
        #pragma unroll
        for (int h = 0; h < 12; ++h) {
            #pragma unroll
            for (int mf = 0; mf < 2; ++mf) {
                const u16* krow = kb +
                    (size_t)(b * 1024 + mbase + mf * 16 + l15) * 768 + h * 64;
                fv4 s = {};
                #pragma unroll
                for (int ks = 0; ks < 2; ++ks) {
                    bfv8 kf = *(const bfv8*)(krow + ks * 32 + l4 * 8);
                    s = __builtin_amdgcn_mfma_f32_16x16x32_bf16(
                            kf, Qf[h][ks], s, 0, 0, 0);
                }
                fv4 e;
                #pragma unroll
                for (int rr = 0; rr < 4; ++rr)
                    e[rr] = __builtin_amdgcn_exp2f(s[rr]);
                dsum[mf] += e;
                E[h][mf] = e;
            }
        }

        fv4 rs[2];
        #pragma unroll
        for (int mf = 0; mf < 2; ++mf)
            #pragma unroll
            for (int rr = 0; rr < 4; ++rr)
                rs[mf][rr] = __builtin_amdgcn_rcpf(dsum[mf][rr]);

        // ---- normalize, pack P, PV ----
        #pragma unroll
        for (int h = 0; h < 12; ++h) {
            uv4 tp;
            tp[0] = cvtpk(E[h][0][0] * rs[0][0], E[h][0][1] * rs[0][1]);
            tp[1] = cvtpk(E[h][0][2] * rs[0][2], E[h][0][3] * rs[0][3]);
            tp[2] = cvtpk(E[h][1][0] * rs[1][0], E[h][1][1] * rs[1][1]);
            tp[3] = cvtpk(E[h][1][2] * rs[1][2], E[h][1][3] * rs[1][3]);
            bfv8 pa = __builtin_bit_cast(bfv8, tp);

            const u16* vbh = vtb + ((size_t)(b * 12 + h) * 64 + l15) * 1024
                             + mbase + l4 * 4;
            #pragma unroll
            for (int dn = 0; dn < 4; ++dn) {
                const u16* vp = vbh + (size_t)dn * 16 * 1024;
                uint2 lo = *(const uint2*)(vp);
                uint2 hi = *(const uint2*)(vp + 16);
                uv4 tv; tv[0] = lo.x; tv[1] = lo.y; tv[2] = hi.x; tv[3] = hi.y;
                bfv8 vf = __builtin_bit_cast(bfv8, tv);
                acc[h][dn] = __builtin_amdgcn_mfma_f32_16x16x32_bf16(
                                 pa, vf, acc[h][dn], 0, 0, 0);
            }
        }
    }

    // ---- pair-reduce over the two m-halves; each wave stores 6 heads ----
    #pragma unroll
    for (int h = 0; h < 12; ++h) {
        if ((h / 6) != mh) {            // not mine to store: publish to LDS
            #pragma unroll
            for (int dn = 0; dn < 4; ++dn)
                red[(h * 4 + dn) * 64 + l] = acc[h][dn];
        }
    }
    __syncthreads();
    #pragma unroll
    for (int h = 0; h < 12; ++h) {
        if ((h / 6) == mh) {
            #pragma unroll
            for (int dn = 0; dn < 4; ++dn) {
                fv4 o = acc[h][dn] + red[(h * 4 + dn) * 64 + l];
                #pragma unroll
                for (int rr = 0; rr < 4; ++rr)
                    ctx[(size_t)(b * 1024 + nbase + l4 * 4 + rr) * 768 +
                        h * 64 + dn * 16 + l15] = f2bf(o[rr]);
            }
        }
    }
}

// ---------------------------------------------------------------------------
extern "C" void kernel_launch(void* const* d_in, const int* in_sizes, int n_in,
                              void* d_out, int out_size, void* d_ws, size_t ws_size,
                              hipStream_t stream)
{
    const float* x  = (const float*)d_in[0];
    const float* Wq = (const float*)d_in[1];
    const float* bq = (const float*)d_in[2];
    const float* Wk = (const float*)d_in[3];
    const float* bk = (const float*)d_in[4];
    const float* Wv = (const float*)d_in[5];
    const float* bv = (const float*)d_in[6];
    const float* Wo = (const float*)d_in[7];
    const float* bo = (const float*)d_in[8];
    float* out = (float*)d_out;

    u16* ws  = (u16*)d_ws;
    u16* xb  = ws;                      // 6291456
    u16* wqb = xb + 6291456;            // 589824 each
    u16* wkb = wqb + 589824;
    u16* wvb = wkb + 589824;
    u16* wob = wvb + 589824;
    u16* qb  = wob + 589824;            // [8192][768] bf16 (scaled)
    u16* kbuf= qb + 6291456;            // [8192][768] bf16
    u16* vtb = kbuf + 6291456;          // [B,H,Dh,N]
    u16* ctx = vtb + 6291456;           // [B,N,768]

    const float qscale = 0.125f * 1.44269504089f;   // scale * log2(e)

    cvt_f32_bf16<<<dim3(8448), dim3(256), 0, stream>>>(x, Wq, Wk, Wv, Wo, ws);

    gemm_bt<<<dim3(64, 6), dim3(256), 0, stream>>>(xb, wqb, bq, qb,  nullptr, qscale, 3);
    gemm_bt<<<dim3(64, 6), dim3(256), 0, stream>>>(xb, wkb, bk, kbuf, nullptr, 1.0f,  3);
    gemm_bt<<<dim3(64, 6), dim3(256), 0, stream>>>(xb, wvb, bv, vtb, nullptr, 1.0f,  1);

    fused_attn<<<dim3(64, 8), dim3(128), 0, stream>>>(qb, kbuf, vtb, ctx);

    gemm_bt<<<dim3(64, 6), dim3(256), 0, stream>>>(ctx, wob, bo, nullptr, out, 1.0f, 2);
}